// Round 2
// baseline (209.651 us; speedup 1.0000x reference)
//
#include <hip/hip_runtime.h>

#define N_NODES 4096
#define C 256
#define NH 4
#define CH 64
#define ROWS 8          // rows per block in k_feats
#define TJ 32           // j per MFMA round
#define JSPLIT 8
#define JSLICE (N_NODES / JSPLIT)   // 512

typedef float f32x4 __attribute__((ext_vector_type(4)));
typedef __bf16 b16x8 __attribute__((ext_vector_type(8)));
typedef unsigned short u16x8 __attribute__((ext_vector_type(8)));

__device__ inline unsigned short f2bf(float f) {
  unsigned u = __float_as_uint(f);
  u += 0x7fffu + ((u >> 16) & 1u);   // RNE
  return (unsigned short)(u >> 16);
}

__device__ inline float fast_exp2(float x) {
#if __has_builtin(__builtin_amdgcn_exp2f)
  return __builtin_amdgcn_exp2f(x);
#else
  return exp2f(x);
#endif
}

// ---------------- Kernel 1: feats = X@W + b (fp32), src/dst, featsT (bf16, transposed)
__global__ __launch_bounds__(256) void k_feats(
    const float* __restrict__ nf, const float* __restrict__ W,
    const float* __restrict__ bias, const float* __restrict__ av,
    unsigned short* __restrict__ featsT, float* __restrict__ srcv,
    float* __restrict__ dstT) {
  __shared__ float xs[ROWS][C];
  const int i0 = blockIdx.x * ROWS;
  const int c = threadIdx.x;
#pragma unroll
  for (int r = 0; r < ROWS; ++r) xs[r][c] = nf[(size_t)(i0 + r) * C + c];
  __syncthreads();

  float acc[ROWS];
  const float bc = bias[c];
#pragma unroll
  for (int r = 0; r < ROWS; ++r) acc[r] = bc;

  for (int k4 = 0; k4 < C / 4; ++k4) {
    float4 xv[ROWS];
#pragma unroll
    for (int r = 0; r < ROWS; ++r) xv[r] = ((const float4*)xs[r])[k4];
#pragma unroll
    for (int kk = 0; kk < 4; ++kk) {
      const float wv = W[(size_t)(k4 * 4 + kk) * C + c];
#pragma unroll
      for (int r = 0; r < ROWS; ++r)
        acc[r] = fmaf(((const float*)&xv[r])[kk], wv, acc[r]);
    }
  }

  const int h = c >> 6, lane = c & 63;
  const float as = av[h * 2 * CH + lane];
  const float ad = av[h * 2 * CH + CH + lane];
  unsigned pk[4];
#pragma unroll
  for (int r = 0; r < ROWS; ++r) {
    const float f = acc[r];
    const unsigned short fb = f2bf(f);
    if (r & 1) pk[r >> 1] |= ((unsigned)fb) << 16; else pk[r >> 1] = (unsigned)fb;
    float p = f * as, d = f * ad;
#pragma unroll
    for (int m = 32; m; m >>= 1) {
      p += __shfl_xor(p, m);
      d += __shfl_xor(d, m);
    }
    if (lane == 0) {
      srcv[(size_t)(i0 + r) * NH + h] = p;       // src[i,h]
      dstT[(size_t)h * N_NODES + i0 + r] = d;    // dstT[h][j]
    }
  }
  uint4 st; st.x = pk[0]; st.y = pk[1]; st.z = pk[2]; st.w = pk[3];
  *((uint4*)(featsT + (size_t)c * N_NODES + i0)) = st;  // featsT[c][i0..i0+7]
}

// ---------------- Kernel 1b: per-head global max of dst (tiny)
__global__ __launch_bounds__(256) void k_dmax(
    const float* __restrict__ dstT, float* __restrict__ dmax) {
  const int h = threadIdx.x >> 6, lane = threadIdx.x & 63;
  float m = -1e30f;
  const float4* d4 = (const float4*)(dstT + (size_t)h * N_NODES);
  for (int it = lane; it < N_NODES / 4; it += 64) {
    float4 v = d4[it];
    m = fmaxf(m, fmaxf(fmaxf(v.x, v.y), fmaxf(v.z, v.w)));
  }
#pragma unroll
  for (int s = 32; s; s >>= 1) m = fmaxf(m, __shfl_xor(m, s));
  if (lane == 0) dmax[h] = m;
}

// ---------------- Kernel 2: masked-softmax attention + PV via MFMA
// wave = 16 i-rows x 4 heads; block = 4 waves (64 rows); no LDS, no barriers.
__global__ __launch_bounds__(256, 2) void k_attn(
    const int* __restrict__ adj, const unsigned short* __restrict__ featsT,
    const float* __restrict__ srcv, const float* __restrict__ dstT,
    const float* __restrict__ dmax, float* __restrict__ pacc,
    float* __restrict__ lpart) {
  const int slice = blockIdx.x;                 // j-slice
  const int wv = threadIdx.x >> 6;              // wave -> 16-row subtile
  const int i0 = blockIdx.y * 64 + wv * 16;
  const int lane = threadIdx.x & 63;
  const int q = lane >> 4, n = lane & 15;
  const int row = i0 + n;

  const float LOG2E = 1.4426950408889634f;
  float s[NH], m2[NH], l[NH];
#pragma unroll
  for (int h = 0; h < NH; ++h) {
    s[h] = srcv[(size_t)row * NH + h];
    const float xm = s[h] + dmax[h];
    m2[h] = fmaxf(xm, 0.2f * xm) * LOG2E;       // leaky(s+Dmax)*log2e
    l[h] = 0.f;
  }

  const f32x4 zero = {0.f, 0.f, 0.f, 0.f};
  f32x4 acc[NH][4];
#pragma unroll
  for (int h = 0; h < NH; ++h)
#pragma unroll
    for (int g = 0; g < 4; ++g) acc[h][g] = zero;

  const int jbase = slice * JSLICE;
  const int* arow = adj + (size_t)row * N_NODES;

  for (int jt = 0; jt < JSLICE / TJ; ++jt) {
    const int jq = jbase + jt * TJ + q * 8;     // this lane's 8 k-positions

    const int4 a0 = *(const int4*)(arow + jq);
    const int4 a1 = *(const int4*)(arow + jq + 4);
    const int aiv[8] = {a0.x, a0.y, a0.z, a0.w, a1.x, a1.y, a1.z, a1.w};

    b16x8 av[NH];
#pragma unroll
    for (int h = 0; h < NH; ++h) {
      const float* dp = dstT + (size_t)h * N_NODES + jq;
      const float4 d0 = *(const float4*)dp;
      const float4 d1 = *(const float4*)(dp + 4);
      const float dv[8] = {d0.x, d0.y, d0.z, d0.w, d1.x, d1.y, d1.z, d1.w};
      u16x8 ua;
#pragma unroll
      for (int jj = 0; jj < 8; ++jj) {
        const float x = s[h] + dv[jj];
        float e = fast_exp2(fmaf(fmaxf(x, 0.2f * x), LOG2E, -m2[h]));
        e = aiv[jj] ? e : 0.0f;
        l[h] += e;
        ua[jj] = f2bf(e);
      }
      av[h] = __builtin_bit_cast(b16x8, ua);
    }

#pragma unroll
    for (int h = 0; h < NH; ++h)
#pragma unroll
      for (int g = 0; g < 4; ++g) {
        const u16x8 bw = *(const u16x8*)(featsT +
            (size_t)(h * CH + g * 16 + n) * N_NODES + jq);
        const b16x8 bv = __builtin_bit_cast(b16x8, bw);
        acc[h][g] = __builtin_amdgcn_mfma_f32_16x16x32_bf16(av[h], bv, acc[h][g], 0, 0, 0);
      }
  }

  // softmax denominators: sum the 4 q-groups (each held distinct k's)
#pragma unroll
  for (int h = 0; h < NH; ++h) {
    l[h] += __shfl_xor(l[h], 16);
    l[h] += __shfl_xor(l[h], 32);
  }
  if (q == 0) {
#pragma unroll
    for (int h = 0; h < NH; ++h)
      lpart[((size_t)slice * N_NODES + row) * NH + h] = l[h];
  }

#pragma unroll
  for (int h = 0; h < NH; ++h)
#pragma unroll
    for (int g = 0; g < 4; ++g)
#pragma unroll
      for (int r = 0; r < 4; ++r) {
        const int orow = i0 + q * 4 + r;          // C/D layout: row = quad*4+reg
        const int ocol = h * CH + g * 16 + n;     // col = lane&15
        pacc[((size_t)slice * N_NODES + orow) * C + ocol] = acc[h][g][r];
      }
}

// ---------------- Kernel 3: combine j-slices, divide by softmax denominator
__global__ __launch_bounds__(256) void k_final(
    const float* __restrict__ pacc, const float* __restrict__ lpart,
    float* __restrict__ out) {
  const int i = blockIdx.x;
  const int c = threadIdx.x;
  const int h = c >> 6;
  float l = 0.f, sacc = 0.f;
#pragma unroll
  for (int sp = 0; sp < JSPLIT; ++sp) {
    l += lpart[((size_t)sp * N_NODES + i) * NH + h];
    sacc += pacc[((size_t)sp * N_NODES + i) * C + c];
  }
  out[(size_t)i * C + c] = sacc / l;
}

extern "C" void kernel_launch(void* const* d_in, const int* in_sizes, int n_in,
                              void* d_out, int out_size, void* d_ws, size_t ws_size,
                              hipStream_t stream) {
  const float* nf   = (const float*)d_in[0];
  const int* adj    = (const int*)d_in[1];
  const float* W    = (const float*)d_in[2];
  const float* bias = (const float*)d_in[3];
  const float* av   = (const float*)d_in[4];
  float* out = (float*)d_out;

  char* ws = (char*)d_ws;
  unsigned short* featsT = (unsigned short*)ws;                         // 2 MB
  float* dstT  = (float*)(ws + (2u << 20));                             // 64 KB
  float* srcv  = (float*)(ws + (2u << 20) + (64u << 10));               // 64 KB
  float* lpart = (float*)(ws + (2u << 20) + (128u << 10));              // 512 KB
  float* dmax  = (float*)(ws + (2u << 20) + (640u << 10));              // 1 KB
  float* pacc  = (float*)(ws + (2u << 20) + (641u << 10));              // 32 MB

  k_feats<<<N_NODES / ROWS, 256, 0, stream>>>(nf, W, bias, av, featsT, srcv, dstT);
  k_dmax<<<1, 256, 0, stream>>>(dstT, dmax);
  dim3 g2(JSPLIT, N_NODES / 64);
  k_attn<<<g2, 256, 0, stream>>>(adj, featsT, srcv, dstT, dmax, pacc, lpart);
  k_final<<<N_NODES, 256, 0, stream>>>(pacc, lpart, out);
}

// Round 3
// 165.265 us; speedup vs baseline: 1.2686x; 1.2686x over previous
//
#include <hip/hip_runtime.h>

#define NN 4096
#define C 256
#define NH 4
#define CH 64
#define JSPLIT 8
#define JSLICE (NN / JSPLIT)     // 512
#define NJT (JSLICE / 32)        // 16

typedef float f32x4 __attribute__((ext_vector_type(4)));
typedef __bf16 b16x8 __attribute__((ext_vector_type(8)));
typedef unsigned short u16x8 __attribute__((ext_vector_type(8)));
typedef unsigned int u32x4 __attribute__((ext_vector_type(4)));

__device__ inline float fast_exp2(float x) {
#if __has_builtin(__builtin_amdgcn_exp2f)
  return __builtin_amdgcn_exp2f(x);
#else
  return exp2f(x);
#endif
}

// pack two f32 -> (bf16(f0) | bf16(f1)<<16), round-half-up via +0x8000, v_perm pack
__device__ inline unsigned pack2bf(float f0, float f1) {
  unsigned u0 = __float_as_uint(f0) + 0x8000u;
  unsigned u1 = __float_as_uint(f1) + 0x8000u;
  return __builtin_amdgcn_perm(u1, u0, 0x07060302u);  // low half <- u0.hi, high <- u1.hi
}

// ---------------- Kernel 0: prep — pack adj to bits, X->bf16, W->bf16 transposed
__global__ __launch_bounds__(256) void k_prep(
    const int* __restrict__ adj, const float* __restrict__ X,
    const float* __restrict__ W, unsigned char* __restrict__ packed,
    unsigned short* __restrict__ Xbf, unsigned short* __restrict__ WT) {
  const int b = blockIdx.x, t = threadIdx.x;
  if (b < 8192) {
    // adj bit-pack: thread -> one output byte = 8 adjacency ints
    const int idx = b * 256 + t;
    const int4 a0 = *(const int4*)(adj + (size_t)idx * 8);
    const int4 a1 = *(const int4*)(adj + (size_t)idx * 8 + 4);
    unsigned m = 0;
    m |= (a0.x != 0) ? 1u : 0u;   m |= (a0.y != 0) ? 2u : 0u;
    m |= (a0.z != 0) ? 4u : 0u;   m |= (a0.w != 0) ? 8u : 0u;
    m |= (a1.x != 0) ? 16u : 0u;  m |= (a1.y != 0) ? 32u : 0u;
    m |= (a1.z != 0) ? 64u : 0u;  m |= (a1.w != 0) ? 128u : 0u;
    packed[idx] = (unsigned char)m;
  } else if (b < 9216) {
    // X fp32 -> bf16 row-major
    const int idx = (b - 8192) * 256 + t;
    const float4 v = ((const float4*)X)[idx];
    uint2 st;
    st.x = pack2bf(v.x, v.y);
    st.y = pack2bf(v.z, v.w);
    ((uint2*)Xbf)[idx] = st;
  } else {
    // W fp32 -> bf16 transposed: WT[c][k] = W[k][c]; coalesced writes
    const int c = b - 9216;          // 0..255
    const float w = W[(size_t)t * C + c];
    WT[(size_t)c * C + t] = (unsigned short)((__float_as_uint(w) + 0x8000u) >> 16);
  }
}

// ---------------- Kernel 1: feats = X@W + b via MFMA; fused src/dst/featsT epilogue
__global__ __launch_bounds__(256) void k_feats(
    const unsigned short* __restrict__ Xbf, const unsigned short* __restrict__ WT,
    const float* __restrict__ bias, const float* __restrict__ av,
    unsigned short* __restrict__ featsT, float* __restrict__ srcv,
    float* __restrict__ dstT) {
  const int i0 = blockIdx.x * 16;
  const int h = threadIdx.x >> 6;        // wave = head = 64-col group
  const int lane = threadIdx.x & 63;
  const int q = lane >> 4, n = lane & 15;
  const int c0 = h * CH;

  const f32x4 zero = {0.f, 0.f, 0.f, 0.f};
  f32x4 acc[4];
#pragma unroll
  for (int g = 0; g < 4; ++g) acc[g] = zero;

  const unsigned short* ap = Xbf + (size_t)(i0 + n) * C + q * 8;
#pragma unroll
  for (int kt = 0; kt < 8; ++kt) {
    const b16x8 aF = __builtin_bit_cast(b16x8, *(const u16x8*)(ap + kt * 32));
#pragma unroll
    for (int g = 0; g < 4; ++g) {
      const b16x8 bF = __builtin_bit_cast(b16x8,
          *(const u16x8*)(WT + (size_t)(c0 + g * 16 + n) * C + kt * 32 + q * 8));
      acc[g] = __builtin_amdgcn_mfma_f32_16x16x32_bf16(aF, bF, acc[g], 0, 0, 0);
    }
  }

  float fb[4][4], asv[4], adv[4];
#pragma unroll
  for (int g = 0; g < 4; ++g) {
    const float bs = bias[c0 + g * 16 + n];
    asv[g] = av[h * 128 + g * 16 + n];
    adv[g] = av[h * 128 + 64 + g * 16 + n];
#pragma unroll
    for (int r = 0; r < 4; ++r) fb[g][r] = acc[g][r] + bs;
  }
  // featsT[c][i] bf16, 4 rows packed per store
#pragma unroll
  for (int g = 0; g < 4; ++g) {
    uint2 st;
    st.x = pack2bf(fb[g][0], fb[g][1]);
    st.y = pack2bf(fb[g][2], fb[g][3]);
    *(uint2*)(featsT + (size_t)(c0 + g * 16 + n) * NN + i0 + q * 4) = st;
  }
  // src/dst: per row r (row = i0+q*4+r), reduce over g in-lane, over n by shfl
#pragma unroll
  for (int r = 0; r < 4; ++r) {
    float p = 0.f, d = 0.f;
#pragma unroll
    for (int g = 0; g < 4; ++g) {
      p = fmaf(fb[g][r], asv[g], p);
      d = fmaf(fb[g][r], adv[g], d);
    }
#pragma unroll
    for (int m = 1; m < 16; m <<= 1) {
      p += __shfl_xor(p, m);
      d += __shfl_xor(d, m);
    }
    if (n == 0) {
      const int row = i0 + q * 4 + r;
      srcv[(size_t)row * NH + h] = p;
      dstT[(size_t)h * NN + row] = d;
    }
  }
}

// ---------------- Kernel 2: masked-softmax attention + PV via MFMA
// wave = 32 rows x 1 head; block = 4 waves (4 heads, shared adj bits via L1).
// Softmax shift = leaky(s+16) (upper bound; cancels exactly). l via MFMA(B=ones).
__global__ __launch_bounds__(256, 4) void k_attn(
    const unsigned char* __restrict__ packed,
    const unsigned short* __restrict__ featsT,
    const float* __restrict__ srcv, const float* __restrict__ dstT,
    _Float16* __restrict__ pacc, float* __restrict__ lpart) {
  const int slice = blockIdx.x;
  const int i0 = blockIdx.y * 32;
  const int h = threadIdx.x >> 6;
  const int lane = threadIdx.x & 63;
  const int q = lane >> 4, n = lane & 15;
  const int jbase = slice * JSLICE;

  const float LOG2E = 1.4426950408889634f;
  const int r0 = i0 + n, r1 = i0 + 16 + n;
  const float s0 = srcv[(size_t)r0 * NH + h];
  const float s1 = srcv[(size_t)r1 * NH + h];
  const float xm0 = s0 + 16.0f, xm1 = s1 + 16.0f;
  const float m20 = fmaxf(xm0, 0.2f * xm0) * LOG2E;
  const float m21 = fmaxf(xm1, 0.2f * xm1) * LOG2E;

  const f32x4 zero = {0.f, 0.f, 0.f, 0.f};
  f32x4 acc0[4], acc1[4], lacc0 = zero, lacc1 = zero;
#pragma unroll
  for (int g = 0; g < 4; ++g) { acc0[g] = zero; acc1[g] = zero; }

  u16x8 ou;
#pragma unroll
  for (int jj = 0; jj < 8; ++jj) ou[jj] = 0x3F80;  // bf16 1.0
  const b16x8 ones = __builtin_bit_cast(b16x8, ou);

  const unsigned char* mp0 = packed + (size_t)r0 * 512 + (jbase >> 3) + q;
  const unsigned char* mp1 = mp0 + 16 * 512;
  const float* dp = dstT + (size_t)h * NN + jbase + q * 8;

  unsigned Mb0 = mp0[0], Mb1 = mp1[0];
  float4 d0 = *(const float4*)dp, d1 = *(const float4*)(dp + 4);

  for (int jt = 0; jt < NJT; ++jt) {
    const int nx = (jt + 1 < NJT) ? jt + 1 : jt;
    const unsigned Mb0n = mp0[nx * 4], Mb1n = mp1[nx * 4];
    const float4 d0n = *(const float4*)(dp + nx * 32);
    const float4 d1n = *(const float4*)(dp + nx * 32 + 4);

    const int jq = jbase + jt * 32 + q * 8;
    b16x8 bF[4];
#pragma unroll
    for (int g = 0; g < 4; ++g)
      bF[g] = __builtin_bit_cast(b16x8,
          *(const u16x8*)(featsT + (size_t)(h * CH + g * 16 + n) * NN + jq));

    const float dv[8] = {d0.x, d0.y, d0.z, d0.w, d1.x, d1.y, d1.z, d1.w};
    u32x4 pk0, pk1;
#pragma unroll
    for (int p = 0; p < 4; ++p) {
      const int j0 = 2 * p, j1 = 2 * p + 1;
      float x, a;
      x = s0 + dv[j0]; a = fmaf(fmaxf(x, 0.2f * x), LOG2E, -m20);
      const float e00 = fast_exp2((Mb0 & (1u << j0)) ? a : -200.0f);
      x = s0 + dv[j1]; a = fmaf(fmaxf(x, 0.2f * x), LOG2E, -m20);
      const float e01 = fast_exp2((Mb0 & (1u << j1)) ? a : -200.0f);
      x = s1 + dv[j0]; a = fmaf(fmaxf(x, 0.2f * x), LOG2E, -m21);
      const float e10 = fast_exp2((Mb1 & (1u << j0)) ? a : -200.0f);
      x = s1 + dv[j1]; a = fmaf(fmaxf(x, 0.2f * x), LOG2E, -m21);
      const float e11 = fast_exp2((Mb1 & (1u << j1)) ? a : -200.0f);
      pk0[p] = pack2bf(e00, e01);
      pk1[p] = pack2bf(e10, e11);
    }
    const b16x8 E0 = __builtin_bit_cast(b16x8, pk0);
    const b16x8 E1 = __builtin_bit_cast(b16x8, pk1);
#pragma unroll
    for (int g = 0; g < 4; ++g) {
      acc0[g] = __builtin_amdgcn_mfma_f32_16x16x32_bf16(E0, bF[g], acc0[g], 0, 0, 0);
      acc1[g] = __builtin_amdgcn_mfma_f32_16x16x32_bf16(E1, bF[g], acc1[g], 0, 0, 0);
    }
    lacc0 = __builtin_amdgcn_mfma_f32_16x16x32_bf16(E0, ones, lacc0, 0, 0, 0);
    lacc1 = __builtin_amdgcn_mfma_f32_16x16x32_bf16(E1, ones, lacc1, 0, 0, 0);
    Mb0 = Mb0n; Mb1 = Mb1n; d0 = d0n; d1 = d1n;
  }

#pragma unroll
  for (int g = 0; g < 4; ++g)
#pragma unroll
    for (int r = 0; r < 4; ++r) {
      const int col = h * CH + g * 16 + n;
      pacc[((size_t)slice * NN + i0 + q * 4 + r) * C + col] = (_Float16)acc0[g][r];
      pacc[((size_t)slice * NN + i0 + 16 + q * 4 + r) * C + col] = (_Float16)acc1[g][r];
    }
  if (n == 0) {
#pragma unroll
    for (int r = 0; r < 4; ++r) {
      lpart[((size_t)slice * NN + i0 + q * 4 + r) * NH + h] = lacc0[r];
      lpart[((size_t)slice * NN + i0 + 16 + q * 4 + r) * NH + h] = lacc1[r];
    }
  }
}

// ---------------- Kernel 3: combine j-slices, divide
__global__ __launch_bounds__(256) void k_final(
    const _Float16* __restrict__ pacc, const float* __restrict__ lpart,
    float* __restrict__ out) {
  const int i = blockIdx.x;
  const int c = threadIdx.x;
  const int h = c >> 6;
  float l = 0.f, sa = 0.f;
#pragma unroll
  for (int sp = 0; sp < JSPLIT; ++sp) {
    l += lpart[((size_t)sp * NN + i) * NH + h];
    sa += (float)pacc[((size_t)sp * NN + i) * C + c];
  }
  out[(size_t)i * C + c] = sa / l;
}

extern "C" void kernel_launch(void* const* d_in, const int* in_sizes, int n_in,
                              void* d_out, int out_size, void* d_ws, size_t ws_size,
                              hipStream_t stream) {
  const float* nf   = (const float*)d_in[0];
  const int* adj    = (const int*)d_in[1];
  const float* W    = (const float*)d_in[2];
  const float* bias = (const float*)d_in[3];
  const float* av   = (const float*)d_in[4];
  float* out = (float*)d_out;

  char* ws = (char*)d_ws;
  unsigned char* packed  = (unsigned char*)ws;                         // 2 MB
  unsigned short* Xbf    = (unsigned short*)(ws + (2u << 20));         // 2 MB
  unsigned short* WT     = (unsigned short*)(ws + (4u << 20));         // 128 KB
  unsigned short* featsT = (unsigned short*)(ws + (4u << 20) + (256u << 10)); // 2 MB
  float* srcv  = (float*)(ws + (6u << 20) + (256u << 10));             // 64 KB
  float* dstT  = (float*)(ws + (6u << 20) + (320u << 10));             // 64 KB
  float* lpart = (float*)(ws + (6u << 20) + (384u << 10));             // 512 KB
  _Float16* pacc = (_Float16*)(ws + (8u << 20));                       // 16 MB

  k_prep<<<9472, 256, 0, stream>>>(adj, nf, W, packed, Xbf, WT);
  k_feats<<<NN / 16, 256, 0, stream>>>(Xbf, WT, bias, av, featsT, srcv, dstT);
  dim3 g2(JSPLIT, NN / 32);
  k_attn<<<g2, 256, 0, stream>>>(packed, featsT, srcv, dstT, pacc, lpart);
  k_final<<<NN, 256, 0, stream>>>(pacc, lpart, out);
}